// Round 1
// baseline (260.922 us; speedup 1.0000x reference)
//
#include <hip/hip_runtime.h>
#include <hip/hip_bf16.h>

// Shapes: input1 (4,128,768) f32, input2 (4,128,768) f32, W (1536,768) f32, b (768,) f32
// out (4,128,128,768) f32: out[b,n,m,o] = p1[b,n,o] + p2[b,m,o] + bias[o]
//   p1 = input1 @ W[:768]   (bias folded in here)
//   p2 = input2 @ W[768:]

#define M_ROWS 512   // 4*128 rows per GEMM
#define KDIM   768
#define NDIM   768
#define BM 64
#define BN 64
#define BK 16

__global__ __launch_bounds__(256) void dual_gemm_kernel(
    const float* __restrict__ A1, const float* __restrict__ A2,
    const float* __restrict__ W,  const float* __restrict__ bias,
    float* __restrict__ P1, float* __restrict__ P2)
{
    const int gemm = blockIdx.z;                 // 0 -> p1 (+bias), 1 -> p2
    const float* __restrict__ A  = gemm ? A2 : A1;
    const float* __restrict__ Wp = W + (size_t)gemm * KDIM * NDIM;
    float* __restrict__ P        = gemm ? P2 : P1;

    __shared__ float As[BM][BK + 1];   // +1 pad: conflict-free scalar writes/reads
    __shared__ float Bs[BK][BN];

    const int tid = threadIdx.x;       // 0..255
    const int tx  = tid & 15;          // output col group
    const int ty  = tid >> 4;          // output row group

    const int row0 = blockIdx.y * BM;
    const int col0 = blockIdx.x * BN;

    // A-tile loader mapping: 4 threads per row, each a float4 of k
    const int a_row = tid >> 2;            // 0..63
    const int a_k4  = (tid & 3) * 4;       // 0,4,8,12
    // B-tile loader mapping: 16 threads per k-row, each a float4 of n
    const int b_k   = tid >> 4;            // 0..15
    const int b_c4  = (tid & 15) * 4;      // 0..60

    float acc[4][4] = {};

    for (int k0 = 0; k0 < KDIM; k0 += BK) {
        const float4 av = *reinterpret_cast<const float4*>(
            &A[(size_t)(row0 + a_row) * KDIM + k0 + a_k4]);
        As[a_row][a_k4 + 0] = av.x;
        As[a_row][a_k4 + 1] = av.y;
        As[a_row][a_k4 + 2] = av.z;
        As[a_row][a_k4 + 3] = av.w;

        const float4 bv = *reinterpret_cast<const float4*>(
            &Wp[(size_t)(k0 + b_k) * NDIM + col0 + b_c4]);
        *reinterpret_cast<float4*>(&Bs[b_k][b_c4]) = bv;

        __syncthreads();

        #pragma unroll
        for (int k = 0; k < BK; ++k) {
            float a_reg[4];
            #pragma unroll
            for (int i = 0; i < 4; ++i) a_reg[i] = As[ty * 4 + i][k];
            const float4 bq = *reinterpret_cast<const float4*>(&Bs[k][tx * 4]);
            const float b_reg[4] = {bq.x, bq.y, bq.z, bq.w};
            #pragma unroll
            for (int i = 0; i < 4; ++i)
                #pragma unroll
                for (int j = 0; j < 4; ++j)
                    acc[i][j] = fmaf(a_reg[i], b_reg[j], acc[i][j]);
        }
        __syncthreads();
    }

    // epilogue: bias folded into P1 only
    float4 badd = make_float4(0.f, 0.f, 0.f, 0.f);
    if (gemm == 0) {
        badd = *reinterpret_cast<const float4*>(&bias[col0 + tx * 4]);
    }
    #pragma unroll
    for (int i = 0; i < 4; ++i) {
        const int row = row0 + ty * 4 + i;
        float4 o;
        o.x = acc[i][0] + badd.x;
        o.y = acc[i][1] + badd.y;
        o.z = acc[i][2] + badd.z;
        o.w = acc[i][3] + badd.w;
        *reinterpret_cast<float4*>(&P[(size_t)row * NDIM + col0 + tx * 4]) = o;
    }
}

// Broadcast add: out[bn, m, o] = p1[bn, o] + p2[b*128+m, o]
// block (64,4): tx -> o4 lane (float4), ty -> m sub-slot; each thread does 4 m's.
// grid (3, 8, 512): x covers 192 float4/row, y covers 128 m in 16-chunks, z = b*128+n
__global__ __launch_bounds__(256) void bcast_add_kernel(
    const float4* __restrict__ P1, const float4* __restrict__ P2,
    float4* __restrict__ out)
{
    const int o4 = blockIdx.x * 64 + threadIdx.x;   // 0..191
    const int bn = blockIdx.z;                      // 0..511
    const int b  = bn >> 7;

    const float4 v1 = P1[(size_t)bn * 192 + o4];

    const int m0 = blockIdx.y * 16 + threadIdx.y * 4;
    #pragma unroll
    for (int j = 0; j < 4; ++j) {
        const int m = m0 + j;
        const float4 v2 = P2[((size_t)(b * 128 + m)) * 192 + o4];
        float4 r;
        r.x = v1.x + v2.x;
        r.y = v1.y + v2.y;
        r.z = v1.z + v2.z;
        r.w = v1.w + v2.w;
        out[((size_t)bn * 128 + m) * 192 + o4] = r;
    }
}

extern "C" void kernel_launch(void* const* d_in, const int* in_sizes, int n_in,
                              void* d_out, int out_size, void* d_ws, size_t ws_size,
                              hipStream_t stream) {
    const float* input1 = (const float*)d_in[0];
    const float* input2 = (const float*)d_in[1];
    const float* W      = (const float*)d_in[2];
    const float* bias   = (const float*)d_in[3];
    float* out = (float*)d_out;

    float* P1 = (float*)d_ws;                      // 512*768 f32 = 1.57 MB
    float* P2 = P1 + (size_t)M_ROWS * NDIM;        // another 1.57 MB

    dim3 ggrid(NDIM / BN, M_ROWS / BM, 2);         // (12, 8, 2)
    dual_gemm_kernel<<<ggrid, dim3(256), 0, stream>>>(input1, input2, W, bias, P1, P2);

    dim3 bgrid(3, 8, 512);
    dim3 bblock(64, 4, 1);
    bcast_add_kernel<<<bgrid, bblock, 0, stream>>>(
        (const float4*)P1, (const float4*)P2, (float4*)out);
}

// Round 2
// 243.324 us; speedup vs baseline: 1.0723x; 1.0723x over previous
//
#include <hip/hip_runtime.h>
#include <hip/hip_bf16.h>

// out[b,n,m,o] = p1[b,n,o] + p2[b,m,o] + bias[o]
//   p1 = input1 @ W[:768] (+bias), p2 = input2 @ W[768:]
// input1/2: (4,128,768) f32, W: (1536,768) f32, b: (768,) f32, out: (4,128,128,768) f32

#define KDIM   768
#define NDIM   768
#define M_ROWS 512
#define BM 64
#define BN 64
#define BK 32
#define NSTEP (KDIM / BK)   // 24

typedef float f32x4 __attribute__((ext_vector_type(4)));

__global__ __launch_bounds__(256) void dgemm_k(
    const float* __restrict__ A1, const float* __restrict__ A2,
    const float* __restrict__ W,  const float* __restrict__ bias,
    float* __restrict__ P1, float* __restrict__ P2)
{
    const int gemm = blockIdx.z;                 // 0 -> p1 (+bias), 1 -> p2
    const float* __restrict__ A  = gemm ? A2 : A1;
    const float* __restrict__ Wp = W + (size_t)gemm * KDIM * NDIM;
    float* __restrict__ P        = gemm ? P2 : P1;

    __shared__ float As[BK][BM];   // TRANSPOSED: As[k][row] -> b128 broadcast reads
    __shared__ float Bs[BK][BN];

    const int tid = threadIdx.x;
    const int tx  = tid & 15;
    const int ty  = tid >> 4;
    const int row0 = blockIdx.y * BM;
    const int col0 = blockIdx.x * BN;

    // A loader: 4 threads/row, each two float4 of k (at a_k and a_k+16)
    const int a_row = tid >> 2;            // 0..63
    const int a_k   = (tid & 3) * 4;       // 0,4,8,12
    // B loader: 8 threads per k-row, each 8 contiguous cols (two float4)
    const int b_k   = tid >> 3;            // 0..31
    const int b_c   = (tid & 7) * 8;       // 0..56

    const float* Arow = A + (size_t)(row0 + a_row) * KDIM;
    const float* Brow = Wp + (size_t)b_k * NDIM + col0 + b_c;

    // prologue: load step-0 tile into registers
    float4 a0 = *reinterpret_cast<const float4*>(Arow + a_k);
    float4 a1 = *reinterpret_cast<const float4*>(Arow + a_k + 16);
    float4 b0 = *reinterpret_cast<const float4*>(Brow);
    float4 b1 = *reinterpret_cast<const float4*>(Brow + 4);

    float acc[4][4] = {};

    for (int step = 0; ; ++step) {
        // regs -> LDS (A transposed)
        As[a_k + 0][a_row]  = a0.x;
        As[a_k + 1][a_row]  = a0.y;
        As[a_k + 2][a_row]  = a0.z;
        As[a_k + 3][a_row]  = a0.w;
        As[a_k + 16][a_row] = a1.x;
        As[a_k + 17][a_row] = a1.y;
        As[a_k + 18][a_row] = a1.z;
        As[a_k + 19][a_row] = a1.w;
        *reinterpret_cast<float4*>(&Bs[b_k][b_c])     = b0;
        *reinterpret_cast<float4*>(&Bs[b_k][b_c + 4]) = b1;
        __syncthreads();

        // prefetch next tile into registers (overlaps with compute below)
        if (step + 1 < NSTEP) {
            const int k0 = (step + 1) * BK;
            a0 = *reinterpret_cast<const float4*>(Arow + k0 + a_k);
            a1 = *reinterpret_cast<const float4*>(Arow + k0 + a_k + 16);
            b0 = *reinterpret_cast<const float4*>(Brow + (size_t)k0 * NDIM);
            b1 = *reinterpret_cast<const float4*>(Brow + (size_t)k0 * NDIM + 4);
        }

        #pragma unroll
        for (int k = 0; k < BK; ++k) {
            const float4 av = *reinterpret_cast<const float4*>(&As[k][ty * 4]);
            const float4 bv = *reinterpret_cast<const float4*>(&Bs[k][tx * 4]);
            const float ar[4] = {av.x, av.y, av.z, av.w};
            const float br[4] = {bv.x, bv.y, bv.z, bv.w};
            #pragma unroll
            for (int i = 0; i < 4; ++i)
                #pragma unroll
                for (int j = 0; j < 4; ++j)
                    acc[i][j] = fmaf(ar[i], br[j], acc[i][j]);
        }

        if (step + 1 == NSTEP) break;
        __syncthreads();
    }

    // epilogue: bias folded into P1 only
    float4 badd = make_float4(0.f, 0.f, 0.f, 0.f);
    if (gemm == 0) {
        badd = *reinterpret_cast<const float4*>(&bias[col0 + tx * 4]);
    }
    #pragma unroll
    for (int i = 0; i < 4; ++i) {
        const int row = row0 + ty * 4 + i;
        float4 o;
        o.x = acc[i][0] + badd.x;
        o.y = acc[i][1] + badd.y;
        o.z = acc[i][2] + badd.z;
        o.w = acc[i][3] + badd.w;
        *reinterpret_cast<float4*>(&P[(size_t)row * NDIM + col0 + tx * 4]) = o;
    }
}

// out[bn, m, o] = p1[bn, o] + p2[b*128+m, o]
// block (64,4): x -> o4 lane (float4), y -> m slot; each thread does 8 m's.
// grid (3, 4, 512): x covers 192 float4/row, y*32+ty*8 covers m, z = bn.
__global__ __launch_bounds__(256) void bcast_k(
    const float4* __restrict__ P1, const float4* __restrict__ P2,
    float4* __restrict__ out)
{
    const int o4 = blockIdx.x * 64 + threadIdx.x;   // 0..191
    const int bn = blockIdx.z;                      // 0..511
    const int b  = bn >> 7;

    const float4 v1 = P1[bn * 192 + o4];

    const int m0 = blockIdx.y * 32 + threadIdx.y * 8;
    const float4* __restrict__ p2p = P2 + (b * 128 + m0) * 192 + o4;
    float4* __restrict__ op = out + ((size_t)(bn * 128 + m0)) * 192 + o4;

    #pragma unroll
    for (int j = 0; j < 8; ++j) {
        const float4 v2 = p2p[j * 192];
        f32x4 r;
        r.x = v1.x + v2.x;
        r.y = v1.y + v2.y;
        r.z = v1.z + v2.z;
        r.w = v1.w + v2.w;
        __builtin_nontemporal_store(r, reinterpret_cast<f32x4*>(&op[(size_t)j * 192]));
    }
}

extern "C" void kernel_launch(void* const* d_in, const int* in_sizes, int n_in,
                              void* d_out, int out_size, void* d_ws, size_t ws_size,
                              hipStream_t stream) {
    const float* input1 = (const float*)d_in[0];
    const float* input2 = (const float*)d_in[1];
    const float* W      = (const float*)d_in[2];
    const float* bias   = (const float*)d_in[3];
    float* out = (float*)d_out;

    float* P1 = (float*)d_ws;                      // 512*768 f32 = 1.57 MB
    float* P2 = P1 + (size_t)M_ROWS * NDIM;        // another 1.57 MB

    dim3 ggrid(NDIM / BN, M_ROWS / BM, 2);         // (12, 8, 2) = 192 blocks
    dgemm_k<<<ggrid, dim3(256), 0, stream>>>(input1, input2, W, bias, P1, P2);

    dim3 bgrid(3, 4, 512);
    dim3 bblock(64, 4, 1);
    bcast_k<<<bgrid, bblock, 0, stream>>>(
        (const float4*)P1, (const float4*)P2, (float4*)out);
}

// Round 3
// 231.565 us; speedup vs baseline: 1.1268x; 1.0508x over previous
//
#include <hip/hip_runtime.h>
#include <hip/hip_bf16.h>

// out[b,n,m,o] = p1[b,n,o] + p2[b,m,o] + bias[o]
//   p1 = input1 @ W[:768] (+bias), p2 = input2 @ W[768:]
// input1/2: (4,128,768) f32, W: (1536,768) f32, b: (768,) f32, out: (4,128,128,768) f32
// GEMM done in bf16 MFMA with hi/lo split: a = ah + al, w = wh + wl,
// p ~= ah*wh + ah*wl + al*wh  (al*wl ~ 2^-18 relative, dropped)

#define KDIM   768
#define NDIM   768
#define M_ROWS 512
#define BM 64
#define BN 64
#define BK 32
#define NSTEP (KDIM / BK)   // 24
#define LDSPAD 40           // shorts per row (80 B, multiple of 16 B)

typedef short  bf16x8 __attribute__((ext_vector_type(8)));
typedef float  f32x4  __attribute__((ext_vector_type(4)));

static __device__ __forceinline__ short f2bf(float x) {
    __hip_bfloat16 h = __float2bfloat16(x);   // RNE
    return __builtin_bit_cast(short, h);
}
static __device__ __forceinline__ float bf2f(short s) {
    unsigned int u = ((unsigned int)(unsigned short)s) << 16;
    return __builtin_bit_cast(float, u);
}

__global__ __launch_bounds__(256) void dgemm_mfma(
    const float* __restrict__ A1, const float* __restrict__ A2,
    const float* __restrict__ W,  const float* __restrict__ bias,
    float* __restrict__ P1, float* __restrict__ P2)
{
    const int gemm = blockIdx.z;
    const float* __restrict__ A  = gemm ? A2 : A1;
    const float* __restrict__ Wp = W + (size_t)gemm * KDIM * NDIM;
    float* __restrict__ P        = gemm ? P2 : P1;

    __shared__ short Ah[BM][LDSPAD];
    __shared__ short Al[BM][LDSPAD];
    __shared__ short Wh[BN][LDSPAD];   // transposed: Wh[n][k]
    __shared__ short Wl[BN][LDSPAD];

    const int tid  = threadIdx.x;
    const int row0 = blockIdx.y * BM;
    const int col0 = blockIdx.x * BN;

    // staging mapping: srow = A-row / W-col, sk8 = k-chunk of 8
    const int srow = tid & 63;
    const int sk8  = (tid >> 6) * 8;

    const float* Ab = A  + (size_t)(row0 + srow) * KDIM + sk8;
    const float* Wb = Wp + (size_t)sk8 * NDIM + col0 + srow;

    // fragment mapping
    const int lane = tid & 63;
    const int wv   = tid >> 6;        // wave id: owns rows [wv*16, wv*16+16)
    const int fr   = lane & 15;
    const int fk   = (lane >> 4) * 8;

    // prologue loads (step 0)
    float4 av0 = *reinterpret_cast<const float4*>(Ab);
    float4 av1 = *reinterpret_cast<const float4*>(Ab + 4);
    float wreg[8];
    #pragma unroll
    for (int i = 0; i < 8; ++i) wreg[i] = Wb[(size_t)i * NDIM];

    f32x4 acc[4] = {};   // 4 n-tiles of 16x16

    for (int step = 0; ; ++step) {
        // convert + pack + write LDS
        {
            float a[8] = {av0.x, av0.y, av0.z, av0.w, av1.x, av1.y, av1.z, av1.w};
            bf16x8 ah, al, wh, wl;
            #pragma unroll
            for (int i = 0; i < 8; ++i) {
                short h = f2bf(a[i]);
                ah[i] = h;
                al[i] = f2bf(a[i] - bf2f(h));
            }
            #pragma unroll
            for (int i = 0; i < 8; ++i) {
                short h = f2bf(wreg[i]);
                wh[i] = h;
                wl[i] = f2bf(wreg[i] - bf2f(h));
            }
            *reinterpret_cast<bf16x8*>(&Ah[srow][sk8]) = ah;
            *reinterpret_cast<bf16x8*>(&Al[srow][sk8]) = al;
            *reinterpret_cast<bf16x8*>(&Wh[srow][sk8]) = wh;
            *reinterpret_cast<bf16x8*>(&Wl[srow][sk8]) = wl;
        }
        __syncthreads();

        // prefetch next K-step into registers (overlaps MFMA below)
        if (step + 1 < NSTEP) {
            const int ks = (step + 1) * BK;
            av0 = *reinterpret_cast<const float4*>(Ab + ks);
            av1 = *reinterpret_cast<const float4*>(Ab + ks + 4);
            #pragma unroll
            for (int i = 0; i < 8; ++i) wreg[i] = Wb[(size_t)(ks + i) * NDIM];
        }

        // fragments + MFMA
        {
            const bf16x8 fa_h = *reinterpret_cast<const bf16x8*>(&Ah[wv * 16 + fr][fk]);
            const bf16x8 fa_l = *reinterpret_cast<const bf16x8*>(&Al[wv * 16 + fr][fk]);
            #pragma unroll
            for (int j = 0; j < 4; ++j) {
                const bf16x8 fw_h = *reinterpret_cast<const bf16x8*>(&Wh[j * 16 + fr][fk]);
                const bf16x8 fw_l = *reinterpret_cast<const bf16x8*>(&Wl[j * 16 + fr][fk]);
                acc[j] = __builtin_amdgcn_mfma_f32_16x16x32_bf16(fa_h, fw_h, acc[j], 0, 0, 0);
                acc[j] = __builtin_amdgcn_mfma_f32_16x16x32_bf16(fa_h, fw_l, acc[j], 0, 0, 0);
                acc[j] = __builtin_amdgcn_mfma_f32_16x16x32_bf16(fa_l, fw_h, acc[j], 0, 0, 0);
            }
        }

        if (step + 1 == NSTEP) break;
        __syncthreads();
    }

    // epilogue: D layout col=lane&15, row=(lane>>4)*4+reg  [verified m89/m91]
    #pragma unroll
    for (int j = 0; j < 4; ++j) {
        const int col = col0 + j * 16 + fr;
        const float bj = (gemm == 0) ? bias[col] : 0.f;
        #pragma unroll
        for (int q = 0; q < 4; ++q) {
            const int row = row0 + wv * 16 + (lane >> 4) * 4 + q;
            P[(size_t)row * NDIM + col] = acc[j][q] + bj;
        }
    }
}

// out[bn, m, o] = p1[bn, o] + p2[b*128+m, o]
// block (64,4): x -> o4 lane (float4), y -> m slot; each thread does 8 m's.
__global__ __launch_bounds__(256) void bcast_k(
    const float4* __restrict__ P1, const float4* __restrict__ P2,
    float4* __restrict__ out)
{
    const int o4 = blockIdx.x * 64 + threadIdx.x;   // 0..191
    const int bn = blockIdx.z;                      // 0..511
    const int b  = bn >> 7;

    const float4 v1 = P1[bn * 192 + o4];

    const int m0 = blockIdx.y * 32 + threadIdx.y * 8;
    const float4* __restrict__ p2p = P2 + (b * 128 + m0) * 192 + o4;
    float4* __restrict__ op = out + ((size_t)(bn * 128 + m0)) * 192 + o4;

    #pragma unroll
    for (int j = 0; j < 8; ++j) {
        const float4 v2 = p2p[j * 192];
        float4 r;
        r.x = v1.x + v2.x;
        r.y = v1.y + v2.y;
        r.z = v1.z + v2.z;
        r.w = v1.w + v2.w;
        op[(size_t)j * 192] = r;
    }
}

extern "C" void kernel_launch(void* const* d_in, const int* in_sizes, int n_in,
                              void* d_out, int out_size, void* d_ws, size_t ws_size,
                              hipStream_t stream) {
    const float* input1 = (const float*)d_in[0];
    const float* input2 = (const float*)d_in[1];
    const float* W      = (const float*)d_in[2];
    const float* bias   = (const float*)d_in[3];
    float* out = (float*)d_out;

    float* P1 = (float*)d_ws;                      // 512*768 f32
    float* P2 = P1 + (size_t)M_ROWS * NDIM;

    dim3 ggrid(NDIM / BN, M_ROWS / BM, 2);         // (12, 8, 2) = 192 blocks
    dgemm_mfma<<<ggrid, dim3(256), 0, stream>>>(input1, input2, W, bias, P1, P2);

    dim3 bgrid(3, 4, 512);
    dim3 bblock(64, 4, 1);
    bcast_k<<<bgrid, bblock, 0, stream>>>(
        (const float4*)P1, (const float4*)P2, (float4*)out);
}

// Round 4
// 228.283 us; speedup vs baseline: 1.1430x; 1.0144x over previous
//
#include <hip/hip_runtime.h>
#include <hip/hip_bf16.h>

// out[b,n,m,o] = p1[b,n,o] + p2[b,m,o] + bias[o]
//   p1 = input1 @ W[:768] (+bias), p2 = input2 @ W[768:]
// input1/2: (4,128,768) f32, W: (1536,768) f32, b: (768,) f32, out: (4,128,128,768) f32
// GEMM in bf16 MFMA, hi/lo split (ah*wh + ah*wl + al*wh), split-K x4 partials,
// tiny reduce kernel sums partials + bias, bcast kernel streams the 201 MB output.

#define KDIM   768
#define NDIM   768
#define M_ROWS 512
#define BM 64
#define BN 64
#define BK 32
#define KSPLIT 4
#define KSLICE (KDIM / KSPLIT)      // 192
#define NSTEP_S (KSLICE / BK)       // 6
#define LDSPAD 40                   // shorts per row (80 B)
#define PSZ (M_ROWS * NDIM)         // floats per partial: 393216
#define PSZ4 (PSZ / 4)              // float4 per partial: 98304

typedef short  bf16x8 __attribute__((ext_vector_type(8)));
typedef float  f32x4  __attribute__((ext_vector_type(4)));

static __device__ __forceinline__ short f2bf(float x) {
    __hip_bfloat16 h = __float2bfloat16(x);   // RNE
    return __builtin_bit_cast(short, h);
}
static __device__ __forceinline__ float bf2f(short s) {
    unsigned int u = ((unsigned int)(unsigned short)s) << 16;
    return __builtin_bit_cast(float, u);
}

// ---------------- kernel 1: split-K partial GEMMs ----------------
// grid (12, 8, 8): x = n-tile, y = row-tile, z = gemm*KSPLIT + kslice
__global__ __launch_bounds__(256) void dgemm_partial(
    const float* __restrict__ A1, const float* __restrict__ A2,
    const float* __restrict__ W, float* __restrict__ Pp)
{
    const int z     = blockIdx.z;
    const int gemm  = z >> 2;
    const int ksl   = z & 3;
    const int kstart = ksl * KSLICE;

    const float* __restrict__ A  = gemm ? A2 : A1;
    const float* __restrict__ Wp = W + (size_t)gemm * KDIM * NDIM;
    float* __restrict__ P        = Pp + (size_t)z * PSZ;

    __shared__ short Ah[BM][LDSPAD];
    __shared__ short Al[BM][LDSPAD];
    __shared__ short Wh[BN][LDSPAD];   // transposed: Wh[n][k]
    __shared__ short Wl[BN][LDSPAD];

    const int tid  = threadIdx.x;
    const int row0 = blockIdx.y * BM;
    const int col0 = blockIdx.x * BN;

    const int srow = tid & 63;
    const int sk8  = (tid >> 6) * 8;

    const float* Ab = A  + (size_t)(row0 + srow) * KDIM + kstart + sk8;
    const float* Wb = Wp + (size_t)(kstart + sk8) * NDIM + col0 + srow;

    const int lane = tid & 63;
    const int wv   = tid >> 6;
    const int fr   = lane & 15;
    const int fk   = (lane >> 4) * 8;

    float4 av0 = *reinterpret_cast<const float4*>(Ab);
    float4 av1 = *reinterpret_cast<const float4*>(Ab + 4);
    float wreg[8];
    #pragma unroll
    for (int i = 0; i < 8; ++i) wreg[i] = Wb[(size_t)i * NDIM];

    f32x4 acc[4] = {};

    for (int step = 0; ; ++step) {
        {
            float a[8] = {av0.x, av0.y, av0.z, av0.w, av1.x, av1.y, av1.z, av1.w};
            bf16x8 ah, al, wh, wl;
            #pragma unroll
            for (int i = 0; i < 8; ++i) {
                short h = f2bf(a[i]);
                ah[i] = h;
                al[i] = f2bf(a[i] - bf2f(h));
            }
            #pragma unroll
            for (int i = 0; i < 8; ++i) {
                short h = f2bf(wreg[i]);
                wh[i] = h;
                wl[i] = f2bf(wreg[i] - bf2f(h));
            }
            *reinterpret_cast<bf16x8*>(&Ah[srow][sk8]) = ah;
            *reinterpret_cast<bf16x8*>(&Al[srow][sk8]) = al;
            *reinterpret_cast<bf16x8*>(&Wh[srow][sk8]) = wh;
            *reinterpret_cast<bf16x8*>(&Wl[srow][sk8]) = wl;
        }
        __syncthreads();

        if (step + 1 < NSTEP_S) {
            const int ks = (step + 1) * BK;
            av0 = *reinterpret_cast<const float4*>(Ab + ks);
            av1 = *reinterpret_cast<const float4*>(Ab + ks + 4);
            #pragma unroll
            for (int i = 0; i < 8; ++i) wreg[i] = Wb[(size_t)(ks + i) * NDIM];
        }

        {
            const bf16x8 fa_h = *reinterpret_cast<const bf16x8*>(&Ah[wv * 16 + fr][fk]);
            const bf16x8 fa_l = *reinterpret_cast<const bf16x8*>(&Al[wv * 16 + fr][fk]);
            #pragma unroll
            for (int j = 0; j < 4; ++j) {
                const bf16x8 fw_h = *reinterpret_cast<const bf16x8*>(&Wh[j * 16 + fr][fk]);
                const bf16x8 fw_l = *reinterpret_cast<const bf16x8*>(&Wl[j * 16 + fr][fk]);
                acc[j] = __builtin_amdgcn_mfma_f32_16x16x32_bf16(fa_h, fw_h, acc[j], 0, 0, 0);
                acc[j] = __builtin_amdgcn_mfma_f32_16x16x32_bf16(fa_h, fw_l, acc[j], 0, 0, 0);
                acc[j] = __builtin_amdgcn_mfma_f32_16x16x32_bf16(fa_l, fw_h, acc[j], 0, 0, 0);
            }
        }

        if (step + 1 == NSTEP_S) break;
        __syncthreads();
    }

    // D layout: col = lane&15, row = (lane>>4)*4 + reg   [verified m89/m91]
    #pragma unroll
    for (int j = 0; j < 4; ++j) {
        const int col = col0 + j * 16 + fr;
        #pragma unroll
        for (int q = 0; q < 4; ++q) {
            const int row = row0 + wv * 16 + (lane >> 4) * 4 + q;
            P[(size_t)row * NDIM + col] = acc[j][q];
        }
    }
}

// ---------------- kernel 2: reduce partials (+bias into p1) ----------------
// 768 blocks x 256 threads; flat over 2*PSZ4 float4.
__global__ __launch_bounds__(256) void reduce_k(
    const float4* __restrict__ Pp, const float4* __restrict__ bias4,
    float4* __restrict__ P1, float4* __restrict__ P2)
{
    const int fi = blockIdx.x * 256 + threadIdx.x;   // 0 .. 196607
    const int g  = (fi >= PSZ4) ? 1 : 0;
    const int r  = fi - g * PSZ4;

    const float4* src = Pp + (size_t)(g * 4) * PSZ4 + r;
    float4 s0 = src[0];
    float4 s1 = src[PSZ4];
    float4 s2 = src[2 * (size_t)PSZ4];
    float4 s3 = src[3 * (size_t)PSZ4];
    float4 s;
    s.x = (s0.x + s1.x) + (s2.x + s3.x);
    s.y = (s0.y + s1.y) + (s2.y + s3.y);
    s.z = (s0.z + s1.z) + (s2.z + s3.z);
    s.w = (s0.w + s1.w) + (s2.w + s3.w);

    if (g == 0) {
        const float4 bv = bias4[r % 192];
        s.x += bv.x; s.y += bv.y; s.z += bv.z; s.w += bv.w;
        P1[r] = s;
    } else {
        P2[r] = s;
    }
}

// ---------------- kernel 3: broadcast add ----------------
// grid (3, 4, 64): x -> o4 tile of 64, y -> m tile of 32, z -> b(2b)*16 + n-tile of 8
// block 256: lane = o4 within tile, wgroup (t>>6) splits the 32 m's.
__global__ __launch_bounds__(256) void bcast_v2(
    const float4* __restrict__ P1, const float4* __restrict__ P2,
    float4* __restrict__ out)
{
    __shared__ f32x4 p2s[32][64];

    const int t     = threadIdx.x;
    const int lane  = t & 63;
    const int wg    = t >> 6;
    const int o4    = blockIdx.x * 64 + lane;        // 0..191
    const int mbase = blockIdx.y * 32;
    const int b     = blockIdx.z >> 4;
    const int nbase = (blockIdx.z & 15) * 8;

    // stage p2 tile: 32 m-rows x 64 o4
    #pragma unroll
    for (int i = 0; i < 8; ++i) {
        const int m = wg * 8 + i;
        p2s[m][lane] = __builtin_bit_cast(f32x4,
            P2[((size_t)(b * 128 + mbase + m)) * 192 + o4]);
    }

    // v1 rows in registers
    f32x4 v1[8];
    #pragma unroll
    for (int n = 0; n < 8; ++n)
        v1[n] = __builtin_bit_cast(f32x4,
            P1[((size_t)(b * 128 + nbase + n)) * 192 + o4]);

    __syncthreads();

    #pragma unroll
    for (int mi = 0; mi < 8; ++mi) {
        const int m = wg * 8 + mi;
        const f32x4 v2 = p2s[m][lane];
        #pragma unroll
        for (int n = 0; n < 8; ++n) {
            f32x4 r = v1[n] + v2;
            f32x4* dst = reinterpret_cast<f32x4*>(
                &out[(((size_t)(b * 128 + nbase + n)) * 128 + mbase + m) * 192 + o4]);
            __builtin_nontemporal_store(r, dst);
        }
    }
}

extern "C" void kernel_launch(void* const* d_in, const int* in_sizes, int n_in,
                              void* d_out, int out_size, void* d_ws, size_t ws_size,
                              hipStream_t stream) {
    const float* input1 = (const float*)d_in[0];
    const float* input2 = (const float*)d_in[1];
    const float* W      = (const float*)d_in[2];
    const float* bias   = (const float*)d_in[3];
    float* out = (float*)d_out;

    float* Pp = (float*)d_ws;                       // 8 partials: 12.6 MB
    float* P1 = Pp + (size_t)8 * PSZ;               // 1.57 MB
    float* P2 = P1 + (size_t)PSZ;                   // 1.57 MB

    dim3 ggrid(NDIM / BN, M_ROWS / BM, 2 * KSPLIT); // (12, 8, 8) = 768 blocks
    dgemm_partial<<<ggrid, dim3(256), 0, stream>>>(input1, input2, W, Pp);

    reduce_k<<<dim3(2 * PSZ4 / 256), dim3(256), 0, stream>>>(
        (const float4*)Pp, (const float4*)bias, (float4*)P1, (float4*)P2);

    dim3 bgrid(3, 4, 64);
    bcast_v2<<<bgrid, dim3(256), 0, stream>>>(
        (const float4*)P1, (const float4*)P2, (float4*)out);
}